// Round 5
// baseline (416.815 us; speedup 1.0000x reference)
//
#include <hip/hip_runtime.h>
#include <math.h>

// Problem constants
constexpr int Bq = 128;   // batch
constexpr int Nn = 512;   // nodes
constexpr int Dd = 300;   // feature dim
constexpr int Aa = 32;    // attention dim
constexpr int DT = 304;   // d padded to 19 tiles of 16 for MFMA N-dim

typedef __attribute__((ext_vector_type(8))) short short8;   // 8 bf16 (4 VGPRs)
typedef __attribute__((ext_vector_type(4))) float float4v;  // MFMA acc

static __device__ __forceinline__ ushort f2bf(float x) {
    unsigned u = __float_as_uint(x);
    return (ushort)((u + 0x7FFF + ((u >> 16) & 1)) >> 16);   // RNE
}

// ---------------- Kernel 1: Q/K projection (bf16 out) + bf16 X^T emission ----------------
constexpr int KB_ROWS = 128;
constexpr int DCHUNK = 100;      // 300 = 3 x 100
constexpr int XS_STRIDE = 102;

__global__ __launch_bounds__(256) void proj_qk(
    const float* __restrict__ X, const float* __restrict__ Wq,
    const float* __restrict__ Wk, ushort* __restrict__ Qo, ushort* __restrict__ Ko,
    ushort* __restrict__ XbfT)
{
    __shared__ float xs[KB_ROWS * XS_STRIDE];  // ~51 KB
    const int b  = blockIdx.y;
    const int n0 = blockIdx.x * KB_ROWS;
    const int t  = threadIdx.x;
    const int c  = t & 15;
    const int r  = t >> 4;
    const int a4 = c * 4;
    const int rbase = r * 8;
    const float* Wbase = (a4 < Aa) ? (Wq + a4) : (Wk + (a4 - Aa));
    const float* Xb = X + ((size_t)(b * Nn + n0)) * Dd;

    float4 acc[8];
#pragma unroll
    for (int j = 0; j < 8; ++j) acc[j] = make_float4(0.f, 0.f, 0.f, 0.f);

    for (int d0 = 0; d0 < Dd; d0 += DCHUNK) {
        for (int l = t; l < KB_ROWS * (DCHUNK / 2); l += 256) {
            int row = l / (DCHUNK / 2);
            int dd2 = l - row * (DCHUNK / 2);
            *(float2*)(xs + row * XS_STRIDE + dd2 * 2) =
                *(const float2*)(Xb + (size_t)row * Dd + d0 + dd2 * 2);
        }
        __syncthreads();
        for (int dd = 0; dd < DCHUNK; ++dd) {
            float4 w4 = *(const float4*)(Wbase + (size_t)(d0 + dd) * Aa);
#pragma unroll
            for (int j = 0; j < 8; ++j) {
                float xv = xs[(rbase + j) * XS_STRIDE + dd];
                acc[j].x += xv * w4.x; acc[j].y += xv * w4.y;
                acc[j].z += xv * w4.z; acc[j].w += xv * w4.w;
            }
        }
        // emit bf16 transposed chunk: XbfT[b][d0+dd][n0+row]
        for (int l = t; l < KB_ROWS * DCHUNK; l += 256) {
            int dd  = l >> 7;        // 12800 = 100 x 128
            int row = l & 127;
            XbfT[((size_t)b * DT + d0 + dd) * Nn + n0 + row] =
                f2bf(xs[row * XS_STRIDE + dd]);
        }
        __syncthreads();
    }

    ushort* Obase = (a4 < Aa) ? (Qo + a4) : (Ko + (a4 - Aa));
#pragma unroll
    for (int j = 0; j < 8; ++j) {
        int n = n0 + rbase + j;
        ushort4 o;
        o.x = f2bf(acc[j].x); o.y = f2bf(acc[j].y);
        o.z = f2bf(acc[j].z); o.w = f2bf(acc[j].w);
        *(ushort4*)(Obase + (size_t)(b * Nn + n) * Aa) = o;
    }
}

// ---------------- Kernel 2: cooperative attention, explicit deep MLP ----------------
// v5 = v4 structure with source-forced memory-level parallelism:
//  - phase 1: ALL K (8x short8) + ALL adjacency (16x float4) loads issued up front
//    (one latency window instead of eight; VGPR=52 in v4 proved the compiler sinks
//    loads to uses -> explicit hoist).
//  - phase 3: ks-outer over the wave's 5 d-tiles; per ks: 2 LDS P-reads feed 10 MFMAs,
//    5 independent X loads, 2-deep rolling prefetch (10 VMEM in flight).
constexpr int TN = 32;

__global__ __launch_bounds__(256, 2) void attn_kernel(
    const float* __restrict__ Adj, const ushort* __restrict__ Qbf,
    const ushort* __restrict__ Kbf, const ushort* __restrict__ XbfT,
    float* __restrict__ Out)
{
    __shared__ __align__(16) ushort fragA[2 * 8192];   // 32 KB, A-frag-layout P (bf16)
    __shared__ __align__(16) float wsum[4][TN];

    // XCD swizzle: each XCD (blk%8) streams all 16 tiles of one batch consecutively
    const int blk  = blockIdx.x;
    const int b    = ((blk >> 7) << 3) | (blk & 7);
    const int n0   = ((blk >> 3) & 15) * TN;

    const int t    = threadIdx.x;
    const int lane = t & 63;
    const int wv   = t >> 6;
    const int dl   = lane & 15;
    const int quad = lane >> 4;

    // ---- Phase 1 loads: hoist EVERYTHING (issue order = consumption order) ----
    short8 qfr[2];   // B-operand: Q rows n0+rs*16+dl, a = quad*8..+7
#pragma unroll
    for (int rs = 0; rs < 2; ++rs)
        qfr[rs] = *(const short8*)(Qbf + ((size_t)(b * Nn + n0 + rs * 16 + dl)) * Aa + quad * 8);

    const ushort* Kb    = Kbf + (size_t)b * Nn * Aa + (size_t)dl * Aa + quad * 8;
    const float*  arow0 = Adj + ((size_t)b * Nn + n0 + dl) * Nn + quad * 4;

    short8 kfr[8];   // K rows for (i, h): A-operand
#pragma unroll
    for (int i = 0; i < 4; ++i) {
        const int m0 = (wv + i * 4) * 32;
        kfr[i * 2]     = *(const short8*)(Kb + (size_t)m0 * Aa);
        kfr[i * 2 + 1] = *(const short8*)(Kb + (size_t)(m0 + 16) * Aa);
    }
    float4 ad[16];   // adjacency fragments for (i, rs, h) — the long-latency stream
#pragma unroll
    for (int i = 0; i < 4; ++i) {
        const int m0 = (wv + i * 4) * 32;
#pragma unroll
        for (int rs = 0; rs < 2; ++rs) {
            const float* ar = arow0 + (size_t)rs * 16 * Nn + m0;
            ad[i * 4 + rs * 2]     = *(const float4*)(ar);        // h=0: m = m0+quad*4+r
            ad[i * 4 + rs * 2 + 1] = *(const float4*)(ar + 16);   // h=1: m = m0+16+quad*4+r
        }
    }

    // ---- Phase 1 compute: S^T = mfma(K, Q); e = adj ? exp(S) : 1 -> fragA ----
    // D-layout: col = lane&15 = q (B free dim), row = quad*4+r = m-local.
    float dsum[2] = {0.f, 0.f};
    // A-frag write base: elem = rs*8192 + ks*512 + (2h+(quad>>1))*128 + dl*8 + (quad&1)*4 + r
    ushort* wpb = fragA + (quad >> 1) * 128 + dl * 8 + (quad & 1) * 4;

#pragma unroll
    for (int i = 0; i < 4; ++i) {
        const int ks = wv + i * 4;
        ushort* wp = wpb + ks * 512;
#pragma unroll
        for (int rs = 0; rs < 2; ++rs) {
            float4 a0 = ad[i * 4 + rs * 2];
            float4 a1 = ad[i * 4 + rs * 2 + 1];
            float4v z = {0.f, 0.f, 0.f, 0.f};
            float4v s0 = __builtin_amdgcn_mfma_f32_16x16x32_bf16(kfr[i * 2],     qfr[rs], z, 0, 0, 0);
            float4v s1 = __builtin_amdgcn_mfma_f32_16x16x32_bf16(kfr[i * 2 + 1], qfr[rs], z, 0, 0, 0);
            float e0 = (a0.x != 0.f) ? __expf(s0[0]) : 1.0f;   // adj==0 -> e=1 exactly
            float e1 = (a0.y != 0.f) ? __expf(s0[1]) : 1.0f;
            float e2 = (a0.z != 0.f) ? __expf(s0[2]) : 1.0f;
            float e3 = (a0.w != 0.f) ? __expf(s0[3]) : 1.0f;
            float e4 = (a1.x != 0.f) ? __expf(s1[0]) : 1.0f;
            float e5 = (a1.y != 0.f) ? __expf(s1[1]) : 1.0f;
            float e6 = (a1.z != 0.f) ? __expf(s1[2]) : 1.0f;
            float e7 = (a1.w != 0.f) ? __expf(s1[3]) : 1.0f;
            dsum[rs] += ((e0 + e1) + (e2 + e3)) + ((e4 + e5) + (e6 + e7));
            uint2 w0, w1;
            w0.x = (unsigned)f2bf(e0) | ((unsigned)f2bf(e1) << 16);
            w0.y = (unsigned)f2bf(e2) | ((unsigned)f2bf(e3) << 16);
            w1.x = (unsigned)f2bf(e4) | ((unsigned)f2bf(e5) << 16);
            w1.y = (unsigned)f2bf(e6) | ((unsigned)f2bf(e7) << 16);
            *(uint2*)(wp + rs * 8192)       = w0;   // h=0 chunk
            *(uint2*)(wp + rs * 8192 + 256) = w1;   // h=1 chunk (+2*128 elems)
        }
    }

    // ---- Phase 2: denominators. q-rows are lane-local (col=dl) -> 2 shuffles/wave ----
#pragma unroll
    for (int rs = 0; rs < 2; ++rs) {
        float v = dsum[rs];
        v += __shfl_xor(v, 16);
        v += __shfl_xor(v, 32);
        if (lane < 16) wsum[wv][rs * 16 + lane] = v;
    }
    __syncthreads();

    // Each lane finishes the cross-wave sum itself (float4 LDS reads, no 2nd barrier)
    float invr0[4], invr1[4];
    {
        float4 s0 = *(const float4*)&wsum[0][quad * 4];
        float4 s1 = *(const float4*)&wsum[0][16 + quad * 4];
#pragma unroll
        for (int w = 1; w < 4; ++w) {
            float4 t0 = *(const float4*)&wsum[w][quad * 4];
            float4 t1 = *(const float4*)&wsum[w][16 + quad * 4];
            s0.x += t0.x; s0.y += t0.y; s0.z += t0.z; s0.w += t0.w;
            s1.x += t1.x; s1.y += t1.y; s1.z += t1.z; s1.w += t1.w;
        }
        invr0[0] = 1.0f / s0.x; invr0[1] = 1.0f / s0.y;
        invr0[2] = 1.0f / s0.z; invr0[3] = 1.0f / s0.w;
        invr1[0] = 1.0f / s1.x; invr1[1] = 1.0f / s1.y;
        invr1[2] = 1.0f / s1.z; invr1[3] = 1.0f / s1.w;
    }

    // ---- Phase 3: ks-outer over the wave's 5 d-tiles; deep MLP ----
    // Wave wv owns tiles {wv, wv+4, wv+8, wv+12} and (wv<3) tile 16+wv.
    const ushort* Xb  = XbfT + ((size_t)b * DT) * Nn;
    const ushort* afp = fragA + (size_t)lane * 8;
    const int dt4 = (wv < 3) ? (16 + wv) : 15;      // wv==3: dummy (valid addr, result unused)

    const ushort* bp[5];
#pragma unroll
    for (int i = 0; i < 4; ++i)
        bp[i] = Xb + (size_t)((wv + i * 4) * 16 + dl) * Nn + quad * 8;
    bp[4] = Xb + (size_t)(dt4 * 16 + dl) * Nn + quad * 8;

    float4v acc[5][2];
#pragma unroll
    for (int i = 0; i < 5; ++i) {
        acc[i][0] = (float4v){0.f, 0.f, 0.f, 0.f};
        acc[i][1] = (float4v){0.f, 0.f, 0.f, 0.f};
    }

    short8 xcur[5], xnxt[5];
#pragma unroll
    for (int i = 0; i < 5; ++i) xcur[i] = *(const short8*)(bp[i]);
#pragma unroll
    for (int i = 0; i < 5; ++i) xnxt[i] = *(const short8*)(bp[i] + 32);

#pragma unroll
    for (int ks = 0; ks < 16; ++ks) {
        short8 p0 = *(const short8*)(afp + ks * 512);
        short8 p1 = *(const short8*)(afp + 8192 + ks * 512);
        short8 xc[5];
#pragma unroll
        for (int i = 0; i < 5; ++i) xc[i] = xcur[i];
#pragma unroll
        for (int i = 0; i < 5; ++i) xcur[i] = xnxt[i];
        if (ks < 14) {
#pragma unroll
            for (int i = 0; i < 5; ++i) xnxt[i] = *(const short8*)(bp[i] + (ks + 2) * 32);
        }
#pragma unroll
        for (int i = 0; i < 5; ++i) {
            acc[i][0] = __builtin_amdgcn_mfma_f32_16x16x32_bf16(p0, xc[i], acc[i][0], 0, 0, 0);
            acc[i][1] = __builtin_amdgcn_mfma_f32_16x16x32_bf16(p1, xc[i], acc[i][1], 0, 0, 0);
        }
    }

    // ---- Stores ----
#pragma unroll
    for (int i = 0; i < 5; ++i) {
        const int dt = (i < 4) ? (wv + i * 4) : dt4;
        const int d  = dt * 16 + dl;
        const bool ok = (i < 4) ? true : (wv < 3 && d < Dd);   // tiles 0..15: d<=255<300
        if (ok) {
#pragma unroll
            for (int r = 0; r < 4; ++r) {
                float* o0 = Out + ((size_t)(b * Nn + n0 + quad * 4 + r)) * Dd;
                float* o1 = Out + ((size_t)(b * Nn + n0 + 16 + quad * 4 + r)) * Dd;
                o0[d] = acc[i][0][r] * invr0[r];
                o1[d] = acc[i][1][r] * invr1[r];
            }
        }
    }
}

// ---------------- launch ----------------
extern "C" void kernel_launch(void* const* d_in, const int* in_sizes, int n_in,
                              void* d_out, int out_size, void* d_ws, size_t ws_size,
                              hipStream_t stream) {
    const float* X   = (const float*)d_in[0];   // [128,512,300]
    const float* Adj = (const float*)d_in[1];   // [128,512,512]
    const float* Wq  = (const float*)d_in[2];   // [300,32]
    const float* Wk  = (const float*)d_in[3];   // [300,32]
    float* Out = (float*)d_out;                 // [128,512,300]

    ushort* Qbf  = (ushort*)d_ws;                                      // 4 MB
    ushort* Kbf  = (ushort*)((char*)d_ws + (size_t)4 * 1024 * 1024);   // 4 MB
    ushort* XbfT = (ushort*)((char*)d_ws + (size_t)8 * 1024 * 1024);   // ~39.9 MB

    proj_qk<<<dim3(Nn / KB_ROWS, Bq), 256, 0, stream>>>(X, Wq, Wk, Qbf, Kbf, XbfT);
    attn_kernel<<<dim3(Bq * Nn / TN), 256, 0, stream>>>(Adj, Qbf, Kbf, XbfT, Out);
}